// Round 13
// baseline (13864.793 us; speedup 1.0000x reference)
//
#include <hip/hip_runtime.h>
#include <hip/hip_bf16.h>
#include <stdint.h>

typedef __bf16 bf16;
typedef __bf16 bf16x8 __attribute__((ext_vector_type(8)));
typedef __bf16 bf16x4 __attribute__((ext_vector_type(4)));
typedef float f32x16 __attribute__((ext_vector_type(16)));
typedef float f32x4 __attribute__((ext_vector_type(4)));

#define LL 1024
#define BB 64
#define HH 512
#define NR 8    // rl WGs, 64 gate-cols each
#define NC 16   // cell WGs, 32 hidden-cols each
#define NWG (NR + NC)
#define NPROD 32              // producer WGs (128 waves = 128 x-proj tiles)
#define NLAUNCH (NWG + NPROD)
#define WSLOT 16              // x-projection ring depth (steps)
#define MFMA32(a, b, c) __builtin_amdgcn_mfma_f32_32x32x16_bf16(a, b, c, 0, 0, 0)

// ---------------- ws layout (bytes) ----------------
#define OFF_X      ((size_t)0)           // [LL][BB][HH] bf16       67,108,864
#define OFF_WGSEL  ((size_t)67108864)    // [1536][512] bf16 (x-side rl,zl,z)
#define OFF_WCIH   ((size_t)68681728)    // [512][512]  bf16 (x-side cell)
#define OFF_WHHZZ  ((size_t)69206016)    // [1024][512] bf16 (h-side zl,z)
#define OFF_HBUF   ((size_t)70254592)    // [2][64][512] bf16
#define OFF_A2     ((size_t)70385664)    // [2][64][512] bf16
#define OFF_CTR    ((size_t)70516736)    // astamp[8]@0, hstamp[16]@64B, xstamp[128]@256B
#define OFF_XS     ((size_t)70517760)    // [WSLOT][128 tiles][64 lanes][16] f32 = 8,388,608

static __device__ __forceinline__ float sigm(float x) {
  return 1.0f / (1.0f + __expf(-x));
}
static __device__ __forceinline__ float tanhx(float x) {
  x = fminf(15.0f, fmaxf(-15.0f, x));
  float e = __expf(2.0f * x);
  return (e - 1.0f) / (e + 1.0f);
}

// ---- MALL-coherent vmem helpers (R3/R6/R9-proven protocol) ----
static __device__ __forceinline__ unsigned ld_stamp(const unsigned* p) {
  unsigned s;
  asm volatile("global_load_dword %0, %1, off sc0 sc1\n\ts_waitcnt vmcnt(0)"
               : "=v"(s) : "v"(p) : "memory");
  return s;
}
static __device__ __forceinline__ void st_stamp(unsigned* p, unsigned v) {
  asm volatile("global_store_dword %0, %1, off sc0 sc1" :: "v"(p), "v"(v) : "memory");
}
static __device__ __forceinline__ void ld_frag(const bf16* p, bf16x8& d) {
  asm volatile("global_load_dwordx4 %0, %1, off sc0 sc1" : "=v"(d) : "v"(p) : "memory");
}
static __device__ __forceinline__ void ld_frag_c(const bf16* p, bf16x8& d) {  // cached
  asm volatile("global_load_dwordx4 %0, %1, off" : "=v"(d) : "v"(p) : "memory");
}
static __device__ __forceinline__ void ld_f4(const float* p, f32x4& d) {
  asm volatile("global_load_dwordx4 %0, %1, off sc0 sc1" : "=v"(d) : "v"(p) : "memory");
}
static __device__ __forceinline__ void st_f4(float* p, f32x4 v) {
  asm volatile("global_store_dwordx4 %0, %1, off sc0 sc1" :: "v"(p), "v"(v) : "memory");
}
static __device__ __forceinline__ void st_u16(bf16* p, unsigned v) {
  asm volatile("global_store_short %0, %1, off sc0 sc1" :: "v"(p), "v"(v) : "memory");
}
#define VWAIT(n) do { asm volatile("s_waitcnt vmcnt(" #n ")" ::: "memory"); \
                      __builtin_amdgcn_sched_barrier(0); } while (0)

// swizzled LDS b-frag read: row i, 8 consecutive k; byte ^= (i&7)<<4
static __device__ __forceinline__ bf16x8 ldsfrag(const bf16* w, int i, int k) {
  unsigned byte = ((unsigned)i << 10) + ((unsigned)k << 1);
  byte ^= ((unsigned)(i & 7) << 4);
  return *(const bf16x8*)((const char*)w + byte);
}

__global__ __launch_bounds__(256) void k_cvt_x(const float* __restrict__ in,
                                               bf16* __restrict__ o) {
  size_t i = ((size_t)blockIdx.x * 256 + threadIdx.x) * 4;
  float4 f = *(const float4*)(in + i);
  bf16x4 v;
  v[0] = (bf16)f.x; v[1] = (bf16)f.y; v[2] = (bf16)f.z; v[3] = (bf16)f.w;
  *(bf16x4*)(o + i) = v;
}

// wgsel: rows {rl:0..511 -> W_gih[0..511], zl:512..1023 -> W_gih[1024..1535],
//              z:1024..1535 -> W_gih[2048..2559]}; wcb = W_cih;
// whhzz: rows {zl:0..511 -> W_glhh[1024..1535], z:512..1023 -> W_glhh[2048..2559]}
__global__ __launch_bounds__(256) void k_cvt_w(const float* __restrict__ wgih,
                                               const float* __restrict__ wcf,
                                               const float* __restrict__ wglhh,
                                               bf16* __restrict__ wgsel,
                                               bf16* __restrict__ wcb,
                                               bf16* __restrict__ whhzz) {
  int i = blockIdx.x * 256 + threadIdx.x;
  const int NQ1 = (1536 * 512) / 4;
  const int NQ2 = (512 * 512) / 4;
  const float* s;
  bf16* d;
  if (i < NQ1) {
    int e = i * 4;
    int p = e >> 9, k = e & 511;
    int src = (p < 512) ? p : ((p < 1024) ? (1024 + p - 512) : (2048 + p - 1024));
    s = wgih + (size_t)src * 512 + k;
    d = wgsel + (size_t)p * 512 + k;
  } else if (i < NQ1 + NQ2) {
    int e = (i - NQ1) * 4;
    int n = e >> 9, k = e & 511;
    s = wcf + (size_t)n * 512 + k;
    d = wcb + (size_t)n * 512 + k;
  } else {
    int e = (i - NQ1 - NQ2) * 4;
    int q = e >> 9, k = e & 511;
    int src = (q < 512) ? (1024 + q) : (2048 + q - 512);
    s = wglhh + (size_t)src * 512 + k;
    d = whhzz + (size_t)q * 512 + k;
  }
  float4 f = *(const float4*)s;
  bf16x4 v;
  v[0] = (bf16)f.x; v[1] = (bf16)f.y; v[2] = (bf16)f.z; v[3] = (bf16)f.w;
  *(bf16x4*)d = v;
}

// 24 workers (single-round coalesced LDS staging of both critical handoffs) +
// 32 producer WGs computing ALL x-projections into a WSLOT ring.
__global__ __launch_bounds__(256) void k_main(
    const bf16* __restrict__ xbf, const bf16* __restrict__ wgsel,
    const bf16* __restrict__ wcb, const bf16* __restrict__ whhzz,
    const float* __restrict__ wglhh, const float* __restrict__ wclhh,
    const float* __restrict__ bg, const float* __restrict__ bc,
    float* __restrict__ out, bf16* __restrict__ hbuf,
    bf16* __restrict__ a2buf, float* __restrict__ xs,
    unsigned* __restrict__ ctrs) {
  __shared__ __align__(16) char smem[128 * 1024];
  bf16* wlds = (bf16*)smem;                     // R: 64KB weights; C: 32KB

  const int wg = blockIdx.x, tid = threadIdx.x;
  const int lane = tid & 63, wave = tid >> 6;
  const int lr = lane & 31, kq = (lane >> 5) * 8;
  unsigned* astamp = ctrs;        // 8 u32 @0
  unsigned* hstamp = ctrs + 16;   // 16 u32 @64B
  unsigned* xstamp = ctrs + 64;   // 128 u32 @256B

  if (wg >= NWG) {
    // ================= producers: x-projections, WSLOT ahead ============
    const int gx = (wg - NWG) * 4 + wave;       // tile 0..127
    const int proj = gx >> 5;
    const int m0 = 32 * ((gx >> 4) & 1);
    const int col = (gx & 15) * 32 + lr;
    float bias;
    const bf16* wb;
    if (proj == 0)      { bias = bg[col];        wb = wgsel + (size_t)col * HH; }
    else if (proj == 1) { bias = bg[1024 + col]; wb = wgsel + (size_t)(512 + col) * HH; }
    else if (proj == 2) { bias = bg[2048 + col]; wb = wgsel + (size_t)(1024 + col) * HH; }
    else                { bias = bc[col];        wb = wcb + (size_t)col * HH; }
    wb += kq;
    float* xsl = xs + ((size_t)gx * 64 + lane) * 16;
    for (int t = 0; t < LL; ++t) {
      if (t >= WSLOT) {  // slot reuse: consumers must be past step t-WSLOT
        const unsigned* sp = hstamp + (lane & 15);
        while (__any((int)(ld_stamp(sp) < (unsigned)(t - WSLOT + 1)))) {}
      }
      f32x16 a;
      #pragma unroll
      for (int r = 0; r < 16; ++r) a[r] = bias;
      const bf16* xa = xbf + (size_t)t * (BB * HH) + (size_t)(m0 + lr) * HH + kq;
      #pragma unroll 4
      for (int kk = 0; kk < 32; ++kk)
        a = MFMA32(*(const bf16x8*)(xa + kk * 16), *(const bf16x8*)(wb + kk * 16), a);
      float* dst = xsl + (size_t)(t & (WSLOT - 1)) * (128 * 64 * 16);
      f32x4 v0, v1, v2, v3;
      #pragma unroll
      for (int e = 0; e < 4; ++e) { v0[e] = a[e]; v1[e] = a[4 + e]; v2[e] = a[8 + e]; v3[e] = a[12 + e]; }
      st_f4(dst, v0); st_f4(dst + 4, v1); st_f4(dst + 8, v2); st_f4(dst + 12, v3);
      asm volatile("s_waitcnt vmcnt(0)" ::: "memory");
      if (lane == 0) st_stamp(xstamp + gx, (unsigned)(t + 1));
    }
    return;
  }
  __builtin_amdgcn_s_setprio(1);  // workers beat producers at issue arbitration

  if (wg < NR) {
    // ================= R: rl gates =================
    bf16* hstage = (bf16*)(smem + 65536);   // 64KB swizzled h(t-1) stage
    const int m0 = 32 * (wave & 1);
    const int lc = 32 * (wave >> 1) + lr;   // local weight row 0..63
    const int p = wg * 64 + lc;             // rl col 0..511
    const int mrow = m0 + 4 * (lane >> 5);
    const int gx = (wave & 1) * 16 + 2 * wg + (wave >> 1);   // proj0 tile

    for (int u = tid; u < 64 * 64; u += 256) {
      int i = u >> 6, k8 = (u & 63) << 3;
      const float* s = wglhh + (size_t)(wg * 64 + i) * HH + k8;
      bf16x8 v;
      #pragma unroll
      for (int j = 0; j < 8; ++j) v[j] = (bf16)s[j];
      unsigned byte = ((unsigned)i << 10) + ((unsigned)k8 << 1);
      byte ^= ((unsigned)(i & 7) << 4);
      *(bf16x8*)((char*)wlds + byte) = v;
    }
    __syncthreads();

    for (int t = 1; t < LL; ++t) {
      {  // poll h(t-1) + x(t)
        const unsigned* sp = hstamp + (lane & 15);
        unsigned tgt = (unsigned)t;
        if (lane == 16) { sp = xstamp + gx; tgt = (unsigned)(t + 1); }
        while (__any((int)(ld_stamp(sp) < tgt))) {}
      }
      __builtin_amdgcn_sched_barrier(0);
      // xs loads + single-round coalesced stage of h(t-1): ONE serial RTT
      const float* xsp = xs + (((size_t)(t & (WSLOT - 1)) * 128 + gx) * 64 + lane) * 16;
      f32x4 xv0, xv1, xv2, xv3;
      ld_f4(xsp, xv0); ld_f4(xsp + 4, xv1); ld_f4(xsp + 8, xv2); ld_f4(xsp + 12, xv3);
      const bf16* hs = hbuf + (size_t)((t - 1) & 1) * (BB * HH);
      bf16x8 tmp[16];
      #pragma unroll
      for (int j = 0; j < 16; ++j) {
        int u = j * 256 + tid;
        ld_frag(hs + (size_t)(u >> 6) * 512 + ((u & 63) << 3), tmp[j]);
      }
      VWAIT(0);
      #pragma unroll
      for (int j = 0; j < 16; ++j) {
        int u = j * 256 + tid;
        unsigned byte = ((unsigned)(u >> 6) << 10) + ((unsigned)((u & 63) << 3) << 1);
        byte ^= ((unsigned)((u >> 6) & 7) << 4);
        *(bf16x8*)((char*)hstage + byte) = tmp[j];
      }
      __syncthreads();
      // ---- GEMM from LDS ----
      f32x16 acc;
      #pragma unroll
      for (int r = 0; r < 16; ++r) acc[r] = 0.0f;
      #pragma unroll 8
      for (int kk = 0; kk < 32; ++kk)
        acc = MFMA32(ldsfrag(hstage, m0 + lr, kk * 16 + kq),
                     ldsfrag(wlds, lc, kk * 16 + kq), acc);
      // ---- publish a2 = sigm(rl) * h_prev (h_prev from LDS) ----
      bf16* ad = a2buf + (size_t)(t & 1) * (BB * HH);
      #pragma unroll
      for (int r = 0; r < 16; ++r) {
        int m = mrow + (r & 3) + 8 * (r >> 2);
        unsigned hb_ = ((unsigned)m << 10) + ((unsigned)p << 1);
        hb_ ^= ((unsigned)(m & 7) << 4);
        float hp = (float)*(const bf16*)((const char*)hstage + hb_);
        float xadd = (r < 4) ? xv0[r & 3] : (r < 8) ? xv1[r & 3]
                   : (r < 12) ? xv2[r & 3] : xv3[r & 3];
        float gg = sigm(acc[r] + xadd);
        bf16 av = (bf16)(gg * hp);
        st_u16(ad + (size_t)m * HH + p, (unsigned)__builtin_bit_cast(unsigned short, av));
      }
      asm volatile("s_waitcnt vmcnt(0)" ::: "memory");
      __syncthreads();
      if (tid == 0) st_stamp(astamp + wg, (unsigned)(t + 1));
    }
  } else {
    // ================= C: cell + zl/z =================
    const int cj = wg - NR;
    bf16* a2st = (bf16*)(smem + 32768);         // 64KB shared staged a2 (swizzled)
    float* zlzs = (float*)(smem + 98304);       // [2][64][32] f32 (16KB)
    const int n = cj * 32 + lr;                 // hidden col
    const bool crit = (wave < 2);
    const int m0 = crit ? 32 * wave : 32 * (wave - 2);
    const int mrow = m0 + 4 * (lane >> 5);
    const int Mq = (m0 >> 5) * 16;
    const int gc = 96 + Mq + cj;                // proj3 tile (cell-x)
    const int gzl = 32 + Mq + cj;               // proj1
    const int gz = 64 + Mq + cj;                // proj2

    for (int u = tid; u < 32 * 64; u += 256) {
      int i = u >> 6, k8 = (u & 63) << 3;
      const float* s = wclhh + (size_t)(cj * 32 + i) * HH + k8;
      bf16x8 v;
      #pragma unroll
      for (int j = 0; j < 8; ++j) v[j] = (bf16)s[j];
      unsigned byte = ((unsigned)i << 10) + ((unsigned)k8 << 1);
      byte ^= ((unsigned)(i & 7) << 4);
      *(bf16x8*)((char*)wlds + byte) = v;
    }
    __syncthreads();

    float hreg[16];
    #pragma unroll
    for (int r = 0; r < 16; ++r) hreg[r] = 0.0f;

    for (int t = 0; t < LL; ++t) {
      if (crit) {
        f32x4 xv0, xv1, xv2, xv3;
        if (t > 0) {
          {  // poll a2(t) + x(t)
            const unsigned* sp = astamp + (lane & 7);
            unsigned tgt = (unsigned)(t + 1);
            if (lane == 8) sp = xstamp + gc;
            while (__any((int)(ld_stamp(sp) < tgt))) {}
          }
          __builtin_amdgcn_sched_barrier(0);
          const float* xsp = xs + (((size_t)(t & (WSLOT - 1)) * 128 + gc) * 64 + lane) * 16;
          ld_f4(xsp, xv0); ld_f4(xsp + 4, xv1); ld_f4(xsp + 8, xv2); ld_f4(xsp + 12, xv3);
          // cooperative single-round stage: this wave's 16 units of 4096
          const bf16* ab = a2buf + (size_t)(t & 1) * (BB * HH);
          bf16x8 tmp[16];
          #pragma unroll
          for (int j = 0; j < 16; ++j) {
            int u = j * 256 + tid;
            ld_frag(ab + (size_t)(u >> 6) * 512 + ((u & 63) << 3), tmp[j]);
          }
          VWAIT(0);
          #pragma unroll
          for (int j = 0; j < 16; ++j) {
            int u = j * 256 + tid;
            unsigned byte = ((unsigned)(u >> 6) << 10) + ((unsigned)((u & 63) << 3) << 1);
            byte ^= ((unsigned)((u >> 6) & 7) << 4);
            *(bf16x8*)((char*)a2st + byte) = tmp[j];
          }
        } else {
          {  // t==0: only x(0) needed
            const unsigned* sp = xstamp + gc;
            while (__any((int)(ld_stamp(sp) < 1u))) {}
          }
          __builtin_amdgcn_sched_barrier(0);
          const float* xsp = xs + ((size_t)gc * 64 + lane) * 16;
          ld_f4(xsp, xv0); ld_f4(xsp + 4, xv1); ld_f4(xsp + 8, xv2); ld_f4(xsp + 12, xv3);
          VWAIT(0);
        }
        __syncthreads();  // STAGE_BAR: a2st + zlzs(t) both valid
        f32x16 acc;
        #pragma unroll
        for (int r = 0; r < 16; ++r) acc[r] = 0.0f;
        if (t > 0) {
          #pragma unroll 8
          for (int kk = 0; kk < 32; ++kk)
            acc = MFMA32(ldsfrag(a2st, m0 + lr, kk * 16 + kq),
                         ldsfrag(wlds, lr, kk * 16 + kq), acc);
        }
        #pragma unroll
        for (int r = 0; r < 16; ++r) {
          float xadd = (r < 4) ? xv0[r & 3] : (r < 8) ? xv1[r & 3]
                     : (r < 12) ? xv2[r & 3] : xv3[r & 3];
          acc[r] += xadd;
        }
        bf16* hd = hbuf + (size_t)(t & 1) * (BB * HH);
        #pragma unroll
        for (int r = 0; r < 16; ++r) {
          int m = mrow + (r & 3) + 8 * (r >> 2);
          float zlv = zlzs[m * 32 + lr];
          float zv = zlzs[2048 + m * 32 + lr];
          float h = zlv * hreg[r] + zv * tanhx(acc[r]);
          hreg[r] = h;
          bf16 hb16 = (bf16)h;
          st_u16(hd + (size_t)m * HH + n, (unsigned)__builtin_bit_cast(unsigned short, hb16));
        }
        asm volatile("s_waitcnt vmcnt(0)" ::: "memory");
      } else {
        // -------- zl/z waves: gate GEMM, then join a2 staging --------
        f32x16 azl, az;
        #pragma unroll
        for (int r = 0; r < 16; ++r) { azl[r] = 0.0f; az[r] = 0.0f; }
        f32x4 l0, l1, l2, l3, z0, z1, z2, z3;
        if (t > 0) {
          {  // poll h(t-1) + x(t)
            const unsigned* sp = hstamp + (lane & 15);
            unsigned tgt = (unsigned)t;
            if (lane == 16) { sp = xstamp + gzl; tgt = (unsigned)(t + 1); }
            if (lane == 17) { sp = xstamp + gz; tgt = (unsigned)(t + 1); }
            while (__any((int)(ld_stamp(sp) < tgt))) {}
          }
          __builtin_amdgcn_sched_barrier(0);
          const float* xl = xs + (((size_t)(t & (WSLOT - 1)) * 128 + gzl) * 64 + lane) * 16;
          const float* xz = xs + (((size_t)(t & (WSLOT - 1)) * 128 + gz) * 64 + lane) * 16;
          ld_f4(xl, l0); ld_f4(xl + 4, l1); ld_f4(xl + 8, l2); ld_f4(xl + 12, l3);
          ld_f4(xz, z0); ld_f4(xz + 4, z1); ld_f4(xz + 8, z2); ld_f4(xz + 12, z3);
          const bf16* hsA = hbuf + (size_t)((t - 1) & 1) * (BB * HH) + (size_t)(m0 + lr) * HH + kq;
          const bf16* bl = whhzz + (size_t)n * HH + kq;
          const bf16* bz = whhzz + (size_t)(512 + n) * HH + kq;
          bf16x8 A[2][4], Wl[2][4], Wz[2][4];
          #pragma unroll
          for (int j = 0; j < 4; ++j) {
            ld_frag(hsA + j * 16, A[0][j]);
            ld_frag_c(bl + j * 16, Wl[0][j]);
            ld_frag_c(bz + j * 16, Wz[0][j]);
          }
          #pragma unroll
          for (int b = 0; b < 8; ++b) {
            const int s = b & 1, ns = s ^ 1;
            if (b < 7) {
              #pragma unroll
              for (int j = 0; j < 4; ++j) {
                ld_frag(hsA + ((b + 1) * 4 + j) * 16, A[ns][j]);
                ld_frag_c(bl + ((b + 1) * 4 + j) * 16, Wl[ns][j]);
                ld_frag_c(bz + ((b + 1) * 4 + j) * 16, Wz[ns][j]);
              }
              VWAIT(12);
            } else {
              VWAIT(0);
            }
            #pragma unroll
            for (int j = 0; j < 4; ++j) {
              azl = MFMA32(A[s][j], Wl[s][j], azl);
              az = MFMA32(A[s][j], Wz[s][j], az);
            }
          }
        } else {
          {
            const unsigned* sp = xstamp + ((lane & 1) ? gz : gzl);
            while (__any((int)(ld_stamp(sp) < 1u))) {}
          }
          __builtin_amdgcn_sched_barrier(0);
          const float* xl = xs + ((size_t)gzl * 64 + lane) * 16;
          const float* xz = xs + ((size_t)gz * 64 + lane) * 16;
          ld_f4(xl, l0); ld_f4(xl + 4, l1); ld_f4(xl + 8, l2); ld_f4(xl + 12, l3);
          ld_f4(xz, z0); ld_f4(xz + 4, z1); ld_f4(xz + 8, z2); ld_f4(xz + 12, z3);
          VWAIT(0);
        }
        #pragma unroll
        for (int r = 0; r < 16; ++r) {
          int m = mrow + (r & 3) + 8 * (r >> 2);
          float xla = (r < 4) ? l0[r & 3] : (r < 8) ? l1[r & 3]
                    : (r < 12) ? l2[r & 3] : l3[r & 3];
          float xza = (r < 4) ? z0[r & 3] : (r < 8) ? z1[r & 3]
                    : (r < 12) ? z2[r & 3] : z3[r & 3];
          zlzs[m * 32 + lr] = sigm(azl[r] + xla);
          zlzs[2048 + m * 32 + lr] = sigm(az[r] + xza);
        }
        if (t > 0) {  // join cooperative a2 staging (slack waves)
          {
            const unsigned* sp = astamp + (lane & 7);
            while (__any((int)(ld_stamp(sp) < (unsigned)(t + 1)))) {}
          }
          __builtin_amdgcn_sched_barrier(0);
          const bf16* ab = a2buf + (size_t)(t & 1) * (BB * HH);
          bf16x8 tmp[16];
          #pragma unroll
          for (int j = 0; j < 16; ++j) {
            int u = j * 256 + tid;
            ld_frag(ab + (size_t)(u >> 6) * 512 + ((u & 63) << 3), tmp[j]);
          }
          VWAIT(0);
          #pragma unroll
          for (int j = 0; j < 16; ++j) {
            int u = j * 256 + tid;
            unsigned byte = ((unsigned)(u >> 6) << 10) + ((unsigned)((u & 63) << 3) << 1);
            byte ^= ((unsigned)((u >> 6) & 7) << 4);
            *(bf16x8*)((char*)a2st + byte) = tmp[j];
          }
        }
        __syncthreads();  // STAGE_BAR
      }
      __syncthreads();  // END: h published (crit) / buffers consumed
      if (tid == 0) st_stamp(hstamp + cj, (unsigned)(t + 1));
      if (crit) {
        // fp32 outputs AFTER the stamp — off the serial chain
        #pragma unroll
        for (int r = 0; r < 16; ++r) {
          int m = mrow + (r & 3) + 8 * (r >> 2);
          out[(size_t)m * (LL * HH) + (size_t)t * HH + n] = hreg[r];
        }
      }
    }
  }
}

extern "C" void kernel_launch(void* const* d_in, const int* in_sizes, int n_in,
                              void* d_out, int out_size, void* d_ws, size_t ws_size,
                              hipStream_t stream) {
  (void)in_sizes; (void)n_in; (void)out_size; (void)ws_size;
  const float* x     = (const float*)d_in[0];
  const float* wgih  = (const float*)d_in[2];
  const float* bg    = (const float*)d_in[3];
  const float* wglhh = (const float*)d_in[4];
  const float* wcihf = (const float*)d_in[6];
  const float* bc    = (const float*)d_in[7];
  const float* wclhh = (const float*)d_in[8];
  float* out = (float*)d_out;

  char* ws = (char*)d_ws;
  bf16* xbf     = (bf16*)(ws + OFF_X);
  bf16* wgsel   = (bf16*)(ws + OFF_WGSEL);
  bf16* wcb     = (bf16*)(ws + OFF_WCIH);
  bf16* whhzz   = (bf16*)(ws + OFF_WHHZZ);
  bf16* hbuf    = (bf16*)(ws + OFF_HBUF);
  bf16* a2buf   = (bf16*)(ws + OFF_A2);
  float* xsb    = (float*)(ws + OFF_XS);
  unsigned* ctr = (unsigned*)(ws + OFF_CTR);

  hipMemsetAsync(ctr, 0, 1024, stream);  // stamps reset every replay
  hipMemsetAsync(out + (size_t)BB * LL * HH, 0, (size_t)BB * HH * sizeof(float), stream);

  k_cvt_x<<<dim3(32768), dim3(256), 0, stream>>>(x, xbf);
  k_cvt_w<<<dim3(1536), dim3(256), 0, stream>>>(wgih, wcihf, wglhh, wgsel, wcb, whhzz);
  k_main<<<dim3(NLAUNCH), dim3(256), 0, stream>>>(xbf, wgsel, wcb, whhzz, wglhh, wclhh,
                                                  bg, bc, out, hbuf, a2buf, xsb, ctr);
}

// Round 14
// 12555.663 us; speedup vs baseline: 1.1043x; 1.1043x over previous
//
#include <hip/hip_runtime.h>
#include <hip/hip_bf16.h>
#include <stdint.h>

typedef __bf16 bf16;
typedef __bf16 bf16x8 __attribute__((ext_vector_type(8)));
typedef __bf16 bf16x4 __attribute__((ext_vector_type(4)));
typedef float f32x16 __attribute__((ext_vector_type(16)));
typedef float f32x4 __attribute__((ext_vector_type(4)));

#define LL 1024
#define BB 64
#define HH 512
#define NR 8    // rl WGs, 64 gate-cols each
#define NC 16   // cell WGs, 32 hidden-cols each
#define NWG (NR + NC)
#define NPROD 32              // producer WGs (128 waves = 128 x-proj tiles)
#define NLAUNCH (NWG + NPROD)
#define WSLOT 16              // x-projection ring depth (steps)
#define MFMA32(a, b, c) __builtin_amdgcn_mfma_f32_32x32x16_bf16(a, b, c, 0, 0, 0)

// ---------------- ws layout (bytes) ----------------
#define OFF_X      ((size_t)0)           // [LL][BB][HH] bf16       67,108,864
#define OFF_WGSEL  ((size_t)67108864)    // [1536][512] bf16 (x-side rl,zl,z)
#define OFF_WCIH   ((size_t)68681728)    // [512][512]  bf16 (x-side cell)
#define OFF_WHHZZ  ((size_t)69206016)    // [1024][512] bf16 (h-side zl,z)
#define OFF_HBUF   ((size_t)70254592)    // [2][64][512] bf16
#define OFF_A2     ((size_t)70385664)    // [2][64][512] bf16
#define OFF_CTR    ((size_t)70516736)    // astamp[8]@0, hstamp[16]@64B, xstamp[128]@256B
#define OFF_XS     ((size_t)70517760)    // [WSLOT][128 tiles][64 lanes][16] f32 = 8,388,608

static __device__ __forceinline__ float sigm(float x) {
  return 1.0f / (1.0f + __expf(-x));
}
static __device__ __forceinline__ float tanhx(float x) {
  x = fminf(15.0f, fmaxf(-15.0f, x));
  float e = __expf(2.0f * x);
  return (e - 1.0f) / (e + 1.0f);
}

// ---- MALL-coherent vmem helpers (R3/R6/R9-proven protocol) ----
static __device__ __forceinline__ unsigned ld_stamp(const unsigned* p) {
  unsigned s;
  asm volatile("global_load_dword %0, %1, off sc0 sc1\n\ts_waitcnt vmcnt(0)"
               : "=v"(s) : "v"(p) : "memory");
  return s;
}
static __device__ __forceinline__ void st_stamp(unsigned* p, unsigned v) {
  asm volatile("global_store_dword %0, %1, off sc0 sc1" :: "v"(p), "v"(v) : "memory");
}
static __device__ __forceinline__ void ld_frag(const bf16* p, bf16x8& d) {
  asm volatile("global_load_dwordx4 %0, %1, off sc0 sc1" : "=v"(d) : "v"(p) : "memory");
}
static __device__ __forceinline__ void ld_frag_c(const bf16* p, bf16x8& d) {  // cached
  asm volatile("global_load_dwordx4 %0, %1, off" : "=v"(d) : "v"(p) : "memory");
}
static __device__ __forceinline__ void ld_f4(const float* p, f32x4& d) {
  asm volatile("global_load_dwordx4 %0, %1, off sc0 sc1" : "=v"(d) : "v"(p) : "memory");
}
static __device__ __forceinline__ void st_f4(float* p, f32x4 v) {
  asm volatile("global_store_dwordx4 %0, %1, off sc0 sc1" :: "v"(p), "v"(v) : "memory");
}
static __device__ __forceinline__ void st_u16(bf16* p, unsigned v) {
  asm volatile("global_store_short %0, %1, off sc0 sc1" :: "v"(p), "v"(v) : "memory");
}
#define VWAIT(n) do { asm volatile("s_waitcnt vmcnt(" #n ")" ::: "memory"); \
                      __builtin_amdgcn_sched_barrier(0); } while (0)

// swizzled LDS b-frag read: row i, 8 consecutive k; byte ^= (i&7)<<4
static __device__ __forceinline__ bf16x8 ldsfrag(const bf16* w, int i, int k) {
  unsigned byte = ((unsigned)i << 10) + ((unsigned)k << 1);
  byte ^= ((unsigned)(i & 7) << 4);
  return *(const bf16x8*)((const char*)w + byte);
}

__global__ __launch_bounds__(256) void k_cvt_x(const float* __restrict__ in,
                                               bf16* __restrict__ o) {
  size_t i = ((size_t)blockIdx.x * 256 + threadIdx.x) * 4;
  float4 f = *(const float4*)(in + i);
  bf16x4 v;
  v[0] = (bf16)f.x; v[1] = (bf16)f.y; v[2] = (bf16)f.z; v[3] = (bf16)f.w;
  *(bf16x4*)(o + i) = v;
}

// wgsel: rows {rl:0..511 -> W_gih[0..511], zl:512..1023 -> W_gih[1024..1535],
//              z:1024..1535 -> W_gih[2048..2559]}; wcb = W_cih;
// whhzz: rows {zl:0..511 -> W_glhh[1024..1535], z:512..1023 -> W_glhh[2048..2559]}
__global__ __launch_bounds__(256) void k_cvt_w(const float* __restrict__ wgih,
                                               const float* __restrict__ wcf,
                                               const float* __restrict__ wglhh,
                                               bf16* __restrict__ wgsel,
                                               bf16* __restrict__ wcb,
                                               bf16* __restrict__ whhzz) {
  int i = blockIdx.x * 256 + threadIdx.x;
  const int NQ1 = (1536 * 512) / 4;
  const int NQ2 = (512 * 512) / 4;
  const float* s;
  bf16* d;
  if (i < NQ1) {
    int e = i * 4;
    int p = e >> 9, k = e & 511;
    int src = (p < 512) ? p : ((p < 1024) ? (1024 + p - 512) : (2048 + p - 1024));
    s = wgih + (size_t)src * 512 + k;
    d = wgsel + (size_t)p * 512 + k;
  } else if (i < NQ1 + NQ2) {
    int e = (i - NQ1) * 4;
    int n = e >> 9, k = e & 511;
    s = wcf + (size_t)n * 512 + k;
    d = wcb + (size_t)n * 512 + k;
  } else {
    int e = (i - NQ1 - NQ2) * 4;
    int q = e >> 9, k = e & 511;
    int src = (q < 512) ? (1024 + q) : (2048 + q - 512);
    s = wglhh + (size_t)src * 512 + k;
    d = whhzz + (size_t)q * 512 + k;
  }
  float4 f = *(const float4*)s;
  bf16x4 v;
  v[0] = (bf16)f.x; v[1] = (bf16)f.y; v[2] = (bf16)f.z; v[3] = (bf16)f.w;
  *(bf16x4*)d = v;
}

// 24 workers (R12 structure; fewer serial staging rounds) + 32 x-proj producers.
__global__ __launch_bounds__(256) void k_main(
    const bf16* __restrict__ xbf, const bf16* __restrict__ wgsel,
    const bf16* __restrict__ wcb, const bf16* __restrict__ whhzz,
    const float* __restrict__ wglhh, const float* __restrict__ wclhh,
    const float* __restrict__ bg, const float* __restrict__ bc,
    float* __restrict__ out, bf16* __restrict__ hbuf,
    bf16* __restrict__ a2buf, float* __restrict__ xs,
    unsigned* __restrict__ ctrs) {
  __shared__ __align__(16) char smem[128 * 1024];
  bf16* wlds = (bf16*)smem;                     // R: 64KB weights; C: 32KB

  const int wg = blockIdx.x, tid = threadIdx.x;
  const int lane = tid & 63, wave = tid >> 6;
  const int lr = lane & 31, kq = (lane >> 5) * 8;
  unsigned* astamp = ctrs;        // 8 u32 @0
  unsigned* hstamp = ctrs + 16;   // 16 u32 @64B
  unsigned* xstamp = ctrs + 64;   // 128 u32 @256B

  if (wg >= NWG) {
    // ================= producers: x-projections, WSLOT ahead ============
    const int gx = (wg - NWG) * 4 + wave;       // tile 0..127
    const int proj = gx >> 5;
    const int m0 = 32 * ((gx >> 4) & 1);
    const int col = (gx & 15) * 32 + lr;
    float bias;
    const bf16* wb;
    if (proj == 0)      { bias = bg[col];        wb = wgsel + (size_t)col * HH; }
    else if (proj == 1) { bias = bg[1024 + col]; wb = wgsel + (size_t)(512 + col) * HH; }
    else if (proj == 2) { bias = bg[2048 + col]; wb = wgsel + (size_t)(1024 + col) * HH; }
    else                { bias = bc[col];        wb = wcb + (size_t)col * HH; }
    wb += kq;
    float* xsl = xs + ((size_t)gx * 64 + lane) * 16;
    for (int t = 0; t < LL; ++t) {
      if (t >= WSLOT) {  // slot reuse: consumers must be past step t-WSLOT
        const unsigned* sp = hstamp + (lane & 15);
        while (__any((int)(ld_stamp(sp) < (unsigned)(t - WSLOT + 1)))) {}
      }
      f32x16 a;
      #pragma unroll
      for (int r = 0; r < 16; ++r) a[r] = bias;
      const bf16* xa = xbf + (size_t)t * (BB * HH) + (size_t)(m0 + lr) * HH + kq;
      #pragma unroll 4
      for (int kk = 0; kk < 32; ++kk)
        a = MFMA32(*(const bf16x8*)(xa + kk * 16), *(const bf16x8*)(wb + kk * 16), a);
      float* dst = xsl + (size_t)(t & (WSLOT - 1)) * (128 * 64 * 16);
      f32x4 v0, v1, v2, v3;
      #pragma unroll
      for (int e = 0; e < 4; ++e) { v0[e] = a[e]; v1[e] = a[4 + e]; v2[e] = a[8 + e]; v3[e] = a[12 + e]; }
      st_f4(dst, v0); st_f4(dst + 4, v1); st_f4(dst + 8, v2); st_f4(dst + 12, v3);
      asm volatile("s_waitcnt vmcnt(0)" ::: "memory");
      if (lane == 0) st_stamp(xstamp + gx, (unsigned)(t + 1));
    }
    return;
  }
  __builtin_amdgcn_s_setprio(1);  // workers beat producers at issue arbitration

  if (wg < NR) {
    // ================= R: rl gates =================
    bf16* hstage = (bf16*)(smem + 65536);   // 64KB swizzled h(t-1) stage
    const int m0 = 32 * (wave & 1);
    const int lc = 32 * (wave >> 1) + lr;   // local weight row 0..63
    const int p = wg * 64 + lc;             // rl col 0..511
    const int mrow = m0 + 4 * (lane >> 5);
    const int gx = (wave & 1) * 16 + 2 * wg + (wave >> 1);   // proj0 tile

    for (int u = tid; u < 64 * 64; u += 256) {
      int i = u >> 6, k8 = (u & 63) << 3;
      const float* s = wglhh + (size_t)(wg * 64 + i) * HH + k8;
      bf16x8 v;
      #pragma unroll
      for (int j = 0; j < 8; ++j) v[j] = (bf16)s[j];
      unsigned byte = ((unsigned)i << 10) + ((unsigned)k8 << 1);
      byte ^= ((unsigned)(i & 7) << 4);
      *(bf16x8*)((char*)wlds + byte) = v;
    }
    __syncthreads();

    for (int t = 1; t < LL; ++t) {
      {  // poll h(t-1) + x(t)
        const unsigned* sp = hstamp + (lane & 15);
        unsigned tgt = (unsigned)t;
        if (lane == 16) { sp = xstamp + gx; tgt = (unsigned)(t + 1); }
        while (__any((int)(ld_stamp(sp) < tgt))) {}
      }
      __builtin_amdgcn_sched_barrier(0);
      // xs loads + SINGLE-round coalesced stage of h(t-1): one serial RTT
      const float* xsp = xs + (((size_t)(t & (WSLOT - 1)) * 128 + gx) * 64 + lane) * 16;
      f32x4 xv0, xv1, xv2, xv3;
      ld_f4(xsp, xv0); ld_f4(xsp + 4, xv1); ld_f4(xsp + 8, xv2); ld_f4(xsp + 12, xv3);
      const bf16* hs = hbuf + (size_t)((t - 1) & 1) * (BB * HH);
      bf16x8 tmp[16];
      #pragma unroll
      for (int j = 0; j < 16; ++j) {
        int u = j * 256 + tid;
        ld_frag(hs + (size_t)(u >> 6) * 512 + ((u & 63) << 3), tmp[j]);
      }
      VWAIT(0);
      #pragma unroll
      for (int j = 0; j < 16; ++j) {
        int u = j * 256 + tid;
        unsigned byte = ((unsigned)(u >> 6) << 10) + ((unsigned)((u & 63) << 3) << 1);
        byte ^= ((unsigned)((u >> 6) & 7) << 4);
        *(bf16x8*)((char*)hstage + byte) = tmp[j];
      }
      __syncthreads();
      // ---- GEMM from LDS ----
      f32x16 acc;
      #pragma unroll
      for (int r = 0; r < 16; ++r) acc[r] = 0.0f;
      #pragma unroll 8
      for (int kk = 0; kk < 32; ++kk)
        acc = MFMA32(ldsfrag(hstage, m0 + lr, kk * 16 + kq),
                     ldsfrag(wlds, lc, kk * 16 + kq), acc);
      // ---- publish a2 = sigm(rl) * h_prev (h_prev from LDS) ----
      bf16* ad = a2buf + (size_t)(t & 1) * (BB * HH);
      #pragma unroll
      for (int r = 0; r < 16; ++r) {
        int m = mrow + (r & 3) + 8 * (r >> 2);
        unsigned hb_ = ((unsigned)m << 10) + ((unsigned)p << 1);
        hb_ ^= ((unsigned)(m & 7) << 4);
        float hp = (float)*(const bf16*)((const char*)hstage + hb_);
        float xadd = (r < 4) ? xv0[r & 3] : (r < 8) ? xv1[r & 3]
                   : (r < 12) ? xv2[r & 3] : xv3[r & 3];
        float gg = sigm(acc[r] + xadd);
        bf16 av = (bf16)(gg * hp);
        st_u16(ad + (size_t)m * HH + p, (unsigned)__builtin_bit_cast(unsigned short, av));
      }
      asm volatile("s_waitcnt vmcnt(0)" ::: "memory");
      __syncthreads();
      if (tid == 0) st_stamp(astamp + wg, (unsigned)(t + 1));
    }
  } else {
    // ================= C: cell + zl/z (R12 wave roles preserved) ==========
    const int cj = wg - NR;
    float* zlzs = (float*)(smem + 32768);       // [2][64][32] f32 (16KB)
    const int n = cj * 32 + lr;                 // hidden col
    const bool crit = (wave < 2);
    const int m0 = crit ? 32 * wave : 32 * (wave - 2);
    const int mrow = m0 + 4 * (lane >> 5);
    const int Mq = (m0 >> 5) * 16;
    const int gc = 96 + Mq + cj;                // proj3 tile (cell-x)
    const int gzl = 32 + Mq + cj;               // proj1
    const int gz = 64 + Mq + cj;                // proj2

    for (int u = tid; u < 32 * 64; u += 256) {
      int i = u >> 6, k8 = (u & 63) << 3;
      const float* s = wclhh + (size_t)(cj * 32 + i) * HH + k8;
      bf16x8 v;
      #pragma unroll
      for (int j = 0; j < 8; ++j) v[j] = (bf16)s[j];
      unsigned byte = ((unsigned)i << 10) + ((unsigned)k8 << 1);
      byte ^= ((unsigned)(i & 7) << 4);
      *(bf16x8*)((char*)wlds + byte) = v;
    }
    __syncthreads();

    float hreg[16];
    #pragma unroll
    for (int r = 0; r < 16; ++r) hreg[r] = 0.0f;

    for (int t = 0; t < LL; ++t) {
      if (crit) {
        f32x16 acc;
        #pragma unroll
        for (int r = 0; r < 16; ++r) acc[r] = 0.0f;
        f32x4 xv0, xv1, xv2, xv3;
        if (t > 0) {
          {  // poll a2(t) + x(t)
            const unsigned* sp = astamp + (lane & 7);
            unsigned tgt = (unsigned)(t + 1);
            if (lane == 8) sp = xstamp + gc;
            while (__any((int)(ld_stamp(sp) < tgt))) {}
          }
          __builtin_amdgcn_sched_barrier(0);
          const float* xsp = xs + (((size_t)(t & (WSLOT - 1)) * 128 + gc) * 64 + lane) * 16;
          ld_f4(xsp, xv0); ld_f4(xsp + 4, xv1); ld_f4(xsp + 8, xv2); ld_f4(xsp + 12, xv3);
          // per-wave coalesced stage of this wave's 32 a2 rows: 2 rounds of 16
          bf16* myst = (bf16*)(smem + 49152 + wave * 32768);   // 32KB each
          const bf16* ab = a2buf + (size_t)(t & 1) * (BB * HH) + (size_t)m0 * HH;
          #pragma unroll
          for (int rnd = 0; rnd < 2; ++rnd) {
            bf16x8 tmp[16];
            #pragma unroll
            for (int j = 0; j < 16; ++j) {
              int u = rnd * 1024 + j * 64 + lane;   // 0..2047 (32 rows x 64 units)
              ld_frag(ab + (size_t)(u >> 6) * 512 + ((u & 63) << 3), tmp[j]);
            }
            VWAIT(0);
            #pragma unroll
            for (int j = 0; j < 16; ++j) {
              int u = rnd * 1024 + j * 64 + lane;
              unsigned byte = ((unsigned)(u >> 6) << 10) + ((unsigned)((u & 63) << 3) << 1);
              byte ^= ((unsigned)((u >> 6) & 7) << 4);
              *(bf16x8*)((char*)myst + byte) = tmp[j];
            }
          }
          asm volatile("s_waitcnt lgkmcnt(0)" ::: "memory");
          __builtin_amdgcn_sched_barrier(0);
          #pragma unroll 8
          for (int kk = 0; kk < 32; ++kk)
            acc = MFMA32(ldsfrag(myst, lr, kk * 16 + kq),
                         ldsfrag(wlds, lr, kk * 16 + kq), acc);
        } else {
          {  // t==0: only x(0) needed
            const unsigned* sp = xstamp + gc;
            while (__any((int)(ld_stamp(sp) < 1u))) {}
          }
          __builtin_amdgcn_sched_barrier(0);
          const float* xsp = xs + ((size_t)gc * 64 + lane) * 16;
          ld_f4(xsp, xv0); ld_f4(xsp + 4, xv1); ld_f4(xsp + 8, xv2); ld_f4(xsp + 12, xv3);
          VWAIT(0);
        }
        #pragma unroll
        for (int r = 0; r < 16; ++r) {
          float xadd = (r < 4) ? xv0[r & 3] : (r < 8) ? xv1[r & 3]
                     : (r < 12) ? xv2[r & 3] : xv3[r & 3];
          acc[r] += xadd;
        }
        __syncthreads();  // MID: zl/z(t) in LDS
        bf16* hd = hbuf + (size_t)(t & 1) * (BB * HH);
        #pragma unroll
        for (int r = 0; r < 16; ++r) {
          int m = mrow + (r & 3) + 8 * (r >> 2);
          float zlv = zlzs[m * 32 + lr];
          float zv = zlzs[2048 + m * 32 + lr];
          float h = zlv * hreg[r] + zv * tanhx(acc[r]);
          hreg[r] = h;
          bf16 hb16 = (bf16)h;
          st_u16(hd + (size_t)m * HH + n, (unsigned)__builtin_bit_cast(unsigned short, hb16));
        }
        asm volatile("s_waitcnt vmcnt(0)" ::: "memory");
      } else {
        f32x16 azl, az;
        #pragma unroll
        for (int r = 0; r < 16; ++r) { azl[r] = 0.0f; az[r] = 0.0f; }
        f32x4 l0, l1, l2, l3, z0, z1, z2, z3;
        if (t > 0) {
          {  // poll h(t-1) + x(t)
            const unsigned* sp = hstamp + (lane & 15);
            unsigned tgt = (unsigned)t;
            if (lane == 16) { sp = xstamp + gzl; tgt = (unsigned)(t + 1); }
            if (lane == 17) { sp = xstamp + gz; tgt = (unsigned)(t + 1); }
            while (__any((int)(ld_stamp(sp) < tgt))) {}
          }
          __builtin_amdgcn_sched_barrier(0);
          const float* xl = xs + (((size_t)(t & (WSLOT - 1)) * 128 + gzl) * 64 + lane) * 16;
          const float* xz = xs + (((size_t)(t & (WSLOT - 1)) * 128 + gz) * 64 + lane) * 16;
          ld_f4(xl, l0); ld_f4(xl + 4, l1); ld_f4(xl + 8, l2); ld_f4(xl + 12, l3);
          ld_f4(xz, z0); ld_f4(xz + 4, z1); ld_f4(xz + 8, z2); ld_f4(xz + 12, z3);
          const bf16* hsA = hbuf + (size_t)((t - 1) & 1) * (BB * HH) + (size_t)(m0 + lr) * HH + kq;
          const bf16* bl = whhzz + (size_t)n * HH + kq;
          const bf16* bz = whhzz + (size_t)(512 + n) * HH + kq;
          bf16x8 A[2][4], Wl[2][4], Wz[2][4];
          #pragma unroll
          for (int j = 0; j < 4; ++j) {
            ld_frag(hsA + j * 16, A[0][j]);
            ld_frag_c(bl + j * 16, Wl[0][j]);
            ld_frag_c(bz + j * 16, Wz[0][j]);
          }
          #pragma unroll
          for (int b = 0; b < 8; ++b) {
            const int s = b & 1, ns = s ^ 1;
            if (b < 7) {
              #pragma unroll
              for (int j = 0; j < 4; ++j) {
                ld_frag(hsA + ((b + 1) * 4 + j) * 16, A[ns][j]);
                ld_frag_c(bl + ((b + 1) * 4 + j) * 16, Wl[ns][j]);
                ld_frag_c(bz + ((b + 1) * 4 + j) * 16, Wz[ns][j]);
              }
              VWAIT(12);
            } else {
              VWAIT(0);
            }
            #pragma unroll
            for (int j = 0; j < 4; ++j) {
              azl = MFMA32(A[s][j], Wl[s][j], azl);
              az = MFMA32(A[s][j], Wz[s][j], az);
            }
          }
        } else {
          {
            const unsigned* sp = xstamp + ((lane & 1) ? gz : gzl);
            while (__any((int)(ld_stamp(sp) < 1u))) {}
          }
          __builtin_amdgcn_sched_barrier(0);
          const float* xl = xs + ((size_t)gzl * 64 + lane) * 16;
          const float* xz = xs + ((size_t)gz * 64 + lane) * 16;
          ld_f4(xl, l0); ld_f4(xl + 4, l1); ld_f4(xl + 8, l2); ld_f4(xl + 12, l3);
          ld_f4(xz, z0); ld_f4(xz + 4, z1); ld_f4(xz + 8, z2); ld_f4(xz + 12, z3);
          VWAIT(0);
        }
        #pragma unroll
        for (int r = 0; r < 16; ++r) {
          int m = mrow + (r & 3) + 8 * (r >> 2);
          float xla = (r < 4) ? l0[r & 3] : (r < 8) ? l1[r & 3]
                    : (r < 12) ? l2[r & 3] : l3[r & 3];
          float xza = (r < 4) ? z0[r & 3] : (r < 8) ? z1[r & 3]
                    : (r < 12) ? z2[r & 3] : z3[r & 3];
          zlzs[m * 32 + lr] = sigm(azl[r] + xla);
          zlzs[2048 + m * 32 + lr] = sigm(az[r] + xza);
        }
        __syncthreads();  // MID
      }
      __syncthreads();  // END: h published (crit) / zlzs consumed next iter
      if (tid == 0) st_stamp(hstamp + cj, (unsigned)(t + 1));
      if (crit) {
        // fp32 outputs AFTER the stamp — off the serial chain
        #pragma unroll
        for (int r = 0; r < 16; ++r) {
          int m = mrow + (r & 3) + 8 * (r >> 2);
          out[(size_t)m * (LL * HH) + (size_t)t * HH + n] = hreg[r];
        }
      }
    }
  }
}

extern "C" void kernel_launch(void* const* d_in, const int* in_sizes, int n_in,
                              void* d_out, int out_size, void* d_ws, size_t ws_size,
                              hipStream_t stream) {
  (void)in_sizes; (void)n_in; (void)out_size; (void)ws_size;
  const float* x     = (const float*)d_in[0];
  const float* wgih  = (const float*)d_in[2];
  const float* bg    = (const float*)d_in[3];
  const float* wglhh = (const float*)d_in[4];
  const float* wcihf = (const float*)d_in[6];
  const float* bc    = (const float*)d_in[7];
  const float* wclhh = (const float*)d_in[8];
  float* out = (float*)d_out;

  char* ws = (char*)d_ws;
  bf16* xbf     = (bf16*)(ws + OFF_X);
  bf16* wgsel   = (bf16*)(ws + OFF_WGSEL);
  bf16* wcb     = (bf16*)(ws + OFF_WCIH);
  bf16* whhzz   = (bf16*)(ws + OFF_WHHZZ);
  bf16* hbuf    = (bf16*)(ws + OFF_HBUF);
  bf16* a2buf   = (bf16*)(ws + OFF_A2);
  float* xsb    = (float*)(ws + OFF_XS);
  unsigned* ctr = (unsigned*)(ws + OFF_CTR);

  hipMemsetAsync(ctr, 0, 1024, stream);  // stamps reset every replay
  hipMemsetAsync(out + (size_t)BB * LL * HH, 0, (size_t)BB * HH * sizeof(float), stream);

  k_cvt_x<<<dim3(32768), dim3(256), 0, stream>>>(x, xbf);
  k_cvt_w<<<dim3(1536), dim3(256), 0, stream>>>(wgih, wcihf, wglhh, wgsel, wcb, whhzz);
  k_main<<<dim3(NLAUNCH), dim3(256), 0, stream>>>(xbf, wgsel, wcb, whhzz, wglhh, wclhh,
                                                  bg, bc, out, hbuf, a2buf, xsb, ctr);
}